// Round 11
// baseline (2412.623 us; speedup 1.0000x reference)
//
#include <hip/hip_runtime.h>
#include <hip/hip_bf16.h>

#define HIDDEN 64
#define TN 64             // nodes per output tile in k_out

static __device__ __forceinline__ unsigned short f2bf(float f) {
    unsigned int u = __float_as_uint(f);
    u += 0x7FFF + ((u >> 16) & 1);        // round-to-nearest-even
    return (unsigned short)(u >> 16);
}
static __device__ __forceinline__ float bf2f(unsigned short s) {
    return __uint_as_float((unsigned int)s << 16);
}
static __device__ __forceinline__ float bflo(unsigned int w) {
    return __uint_as_float(w << 16);
}
static __device__ __forceinline__ float bfhi(unsigned int w) {
    return __uint_as_float(w & 0xFFFF0000u);
}

// ---------------------------------------------------------------------------
// CSR build step 1: degree histogram over dst
// ---------------------------------------------------------------------------
__global__ __launch_bounds__(256) void k_hist(
    const int* __restrict__ ei, int* __restrict__ deg, int nEdges)
{
    for (int e = blockIdx.x * blockDim.x + threadIdx.x; e < nEdges;
         e += gridDim.x * blockDim.x) {
        atomicAdd(&deg[ei[nEdges + e]], 1);
    }
}

// ---------------------------------------------------------------------------
// Two-level parallel exclusive scan
// ---------------------------------------------------------------------------
__global__ __launch_bounds__(256) void k_scan1(
    const int* __restrict__ deg, int* __restrict__ rowPtr,
    int* __restrict__ blockSum, int n)
{
    __shared__ int tmp[256];
    const int t = threadIdx.x;
    const int i = blockIdx.x * 256 + t;
    const int v = (i < n) ? deg[i] : 0;
    tmp[t] = v;
    __syncthreads();
#pragma unroll
    for (int off = 1; off < 256; off <<= 1) {
        const int u = (t >= off) ? tmp[t - off] : 0;
        __syncthreads();
        tmp[t] += u;
        __syncthreads();
    }
    if (i < n) rowPtr[i] = tmp[t] - v;
    if (t == 255) blockSum[blockIdx.x] = tmp[255];
}

__global__ __launch_bounds__(512) void k_scan2(
    int* __restrict__ blockSum, int* __restrict__ rowPtr, int nb, int n)
{
    __shared__ int tmp[512];
    const int t = threadIdx.x;
    const int v = (t < nb) ? blockSum[t] : 0;
    tmp[t] = v;
    __syncthreads();
#pragma unroll
    for (int off = 1; off < 512; off <<= 1) {
        const int u = (t >= off) ? tmp[t - off] : 0;
        __syncthreads();
        tmp[t] += u;
        __syncthreads();
    }
    if (t < nb) blockSum[t] = tmp[t] - v;
    if (t == nb - 1) rowPtr[n] = tmp[t];
}

__global__ __launch_bounds__(256) void k_scan3(
    int* __restrict__ rowPtr, int* __restrict__ cursor,
    const int* __restrict__ blockSum, int n)
{
    const int i = blockIdx.x * 256 + threadIdx.x;
    if (i < n) {
        const int v = rowPtr[i] + blockSum[blockIdx.x];
        rowPtr[i] = v;
        cursor[i] = v;
    }
}

// ---------------------------------------------------------------------------
// CSR fill (plain src ids; order within a node's list arbitrary)
// ---------------------------------------------------------------------------
__global__ __launch_bounds__(256) void k_fill(
    const int* __restrict__ ei, int* __restrict__ cursor,
    int* __restrict__ csrSrc, int nEdges)
{
    for (int e = blockIdx.x * blockDim.x + threadIdx.x; e < nEdges;
         e += gridDim.x * blockDim.x) {
        const int dst = ei[nEdges + e];
        const int pos = atomicAdd(&cursor[dst], 1);
        csrSrc[pos] = ei[e];
    }
}

// ---------------------------------------------------------------------------
// fp32 -> bf16 conversion, 8 elems/thread
// ---------------------------------------------------------------------------
__global__ __launch_bounds__(256) void k_tobf16(
    const float* __restrict__ src, unsigned short* __restrict__ dst, int n8)
{
    for (int i = blockIdx.x * 256 + threadIdx.x; i < n8; i += gridDim.x * 256) {
        const float4 a = ((const float4*)src)[2 * i];
        const float4 b = ((const float4*)src)[2 * i + 1];
        uint4 o;
        o.x = (unsigned)f2bf(a.x) | ((unsigned)f2bf(a.y) << 16);
        o.y = (unsigned)f2bf(a.z) | ((unsigned)f2bf(a.w) << 16);
        o.z = (unsigned)f2bf(b.x) | ((unsigned)f2bf(b.y) << 16);
        o.w = (unsigned)f2bf(b.z) | ((unsigned)f2bf(b.w) << 16);
        ((uint4*)dst)[i] = o;
    }
}

// ---------------------------------------------------------------------------
// Mean-aggregate (gather only): one 64-lane wave per node, lane = feature.
// bf16 gather rows (128B coalesced), fp32 accumulate, bf16 mean out.
// Zero LDS, ~30 VGPR -> 8 blocks/CU. 8 loads in flight, 2 add chains.
// ---------------------------------------------------------------------------
__global__ __launch_bounds__(256, 8) void k_agg(
    const unsigned short* __restrict__ gtab,   // [N,64] bf16
    const int* __restrict__ rowPtr,            // [N+1]
    const int* __restrict__ csrSrc,            // [E]
    unsigned short* __restrict__ meanb,        // [N,64] bf16 out
    int nNodes)
{
    const int node = blockIdx.x * 4 + (threadIdx.x >> 6);
    const int lane = threadIdx.x & 63;
    if (node >= nNodes) return;
    const int beg = rowPtr[node], end = rowPtr[node + 1];
    float a0 = 0.f, a1 = 0.f;
    int i = beg;
#pragma unroll 1
    for (; i + 7 < end; i += 8) {
        const int s0 = csrSrc[i + 0], s1 = csrSrc[i + 1];
        const int s2 = csrSrc[i + 2], s3 = csrSrc[i + 3];
        const int s4 = csrSrc[i + 4], s5 = csrSrc[i + 5];
        const int s6 = csrSrc[i + 6], s7 = csrSrc[i + 7];
        a0 += bf2f(gtab[s0 * HIDDEN + lane]) + bf2f(gtab[s1 * HIDDEN + lane])
            + bf2f(gtab[s2 * HIDDEN + lane]) + bf2f(gtab[s3 * HIDDEN + lane]);
        a1 += bf2f(gtab[s4 * HIDDEN + lane]) + bf2f(gtab[s5 * HIDDEN + lane])
            + bf2f(gtab[s6 * HIDDEN + lane]) + bf2f(gtab[s7 * HIDDEN + lane]);
    }
#pragma unroll 1
    for (; i + 3 < end; i += 4) {
        const int s0 = csrSrc[i + 0], s1 = csrSrc[i + 1];
        const int s2 = csrSrc[i + 2], s3 = csrSrc[i + 3];
        a0 += bf2f(gtab[s0 * HIDDEN + lane]) + bf2f(gtab[s1 * HIDDEN + lane]);
        a1 += bf2f(gtab[s2 * HIDDEN + lane]) + bf2f(gtab[s3 * HIDDEN + lane]);
    }
#pragma unroll 1
    for (; i < end; ++i) a0 += bf2f(gtab[csrSrc[i] * HIDDEN + lane]);
    const float inv = (end > beg) ? 1.0f / (float)(end - beg) : 1.0f;
    meanb[node * HIDDEN + lane] = f2bf((a0 + a1) * inv);
}

// ---------------------------------------------------------------------------
// Output GEMM: out = mean @ Wl + bl + root @ Wr   (optional ReLU, f32|bf16 out)
// One block per 64-node tile; 256 threads = 16x16, 4 nodes x 4 cols each.
// LDS = weights only (32 KB) -> 4 blocks/CU. A (mean/root, bf16) read straight
// from global: within a wave, 16 lanes share each row address -> HW broadcast.
// Single barrier; no split-K; no A tile staging.
// ---------------------------------------------------------------------------
template <bool RELU, bool OUTB>
__global__ __launch_bounds__(256, 4) void k_out(
    const unsigned short* __restrict__ meanb,  // [N,64] bf16
    const unsigned short* __restrict__ rootb,  // [N,64] bf16
    const float* __restrict__ Wl,              // [64,64]
    const float* __restrict__ bl,              // [64]
    const float* __restrict__ Wr,              // [64,64]
    float* __restrict__ outf,                  // f32 out (or null)
    unsigned short* __restrict__ outb,         // bf16 out (or null)
    int nNodes)
{
    __shared__ float sWl[HIDDEN][HIDDEN];
    __shared__ float sWr[HIDDEN][HIDDEN];

    const int tid = threadIdx.x;
    for (int i = tid; i < HIDDEN * HIDDEN; i += 256) {
        sWl[i >> 6][i & 63] = Wl[i];
        sWr[i >> 6][i & 63] = Wr[i];
    }

    const int tr = tid >> 4;      // 0..15: node group (4 nodes)
    const int tc = tid & 15;      // 0..15: col group (4 cols)
    const int base = blockIdx.x * TN;

    // bias loaded BEFORE the barrier (hide latency under weight staging)
    const float b0 = bl[tc * 4 + 0], b1 = bl[tc * 4 + 1];
    const float b2 = bl[tc * 4 + 2], b3 = bl[tc * 4 + 3];

    float acc[4][4];
#pragma unroll
    for (int r = 0; r < 4; ++r) {
        acc[r][0] = b0; acc[r][1] = b1; acc[r][2] = b2; acc[r][3] = b3;
    }
    int gr[4];
#pragma unroll
    for (int r = 0; r < 4; ++r) {
        const int g = base + tr * 4 + r;
        gr[r] = (g < nNodes) ? g : (nNodes - 1);   // clamp; store is guarded
    }
    __syncthreads();   // weights staged

#pragma unroll
    for (int k8 = 0; k8 < 8; ++k8) {
        unsigned int am[4][4], ar[4][4];
#pragma unroll
        for (int r = 0; r < 4; ++r) {
            const uint4 m4 = *(const uint4*)&meanb[gr[r] * HIDDEN + k8 * 8];
            const uint4 r4 = *(const uint4*)&rootb[gr[r] * HIDDEN + k8 * 8];
            am[r][0] = m4.x; am[r][1] = m4.y; am[r][2] = m4.z; am[r][3] = m4.w;
            ar[r][0] = r4.x; ar[r][1] = r4.y; ar[r][2] = r4.z; ar[r][3] = r4.w;
        }
#pragma unroll
        for (int kk = 0; kk < 8; ++kk) {
            const float4 wl4 = *(const float4*)&sWl[k8 * 8 + kk][tc * 4];
            const float4 wr4 = *(const float4*)&sWr[k8 * 8 + kk][tc * 4];
#pragma unroll
            for (int r = 0; r < 4; ++r) {
                const unsigned int wm = am[r][kk >> 1];
                const unsigned int wq = ar[r][kk >> 1];
                const float aM = (kk & 1) ? bfhi(wm) : bflo(wm);
                const float aR = (kk & 1) ? bfhi(wq) : bflo(wq);
                acc[r][0] = fmaf(aM, wl4.x, fmaf(aR, wr4.x, acc[r][0]));
                acc[r][1] = fmaf(aM, wl4.y, fmaf(aR, wr4.y, acc[r][1]));
                acc[r][2] = fmaf(aM, wl4.z, fmaf(aR, wr4.z, acc[r][2]));
                acc[r][3] = fmaf(aM, wl4.w, fmaf(aR, wr4.w, acc[r][3]));
            }
        }
    }

#pragma unroll
    for (int r = 0; r < 4; ++r) {
        const int g = base + tr * 4 + r;
        if (g < nNodes) {
            float o0 = acc[r][0], o1 = acc[r][1], o2 = acc[r][2], o3 = acc[r][3];
            if (RELU) {
                o0 = fmaxf(o0, 0.f); o1 = fmaxf(o1, 0.f);
                o2 = fmaxf(o2, 0.f); o3 = fmaxf(o3, 0.f);
            }
            if (OUTB) {
                ushort4 q;
                q.x = f2bf(o0); q.y = f2bf(o1); q.z = f2bf(o2); q.w = f2bf(o3);
                *(ushort4*)&outb[g * HIDDEN + tc * 4] = q;
            } else {
                float4 o; o.x = o0; o.y = o1; o.z = o2; o.w = o3;
                *(float4*)&outf[g * HIDDEN + tc * 4] = o;
            }
        }
    }
}

extern "C" void kernel_launch(void* const* d_in, const int* in_sizes, int n_in,
                              void* d_out, int out_size, void* d_ws, size_t ws_size,
                              hipStream_t stream)
{
    const float* x   = (const float*)d_in[0];
    const int*   ei  = (const int*)d_in[1];   // [2,E]
    const float* W1l = (const float*)d_in[2];
    const float* b1l = (const float*)d_in[3];
    const float* W1r = (const float*)d_in[4];
    const float* W2l = (const float*)d_in[5];
    const float* b2l = (const float*)d_in[6];
    const float* W2r = (const float*)d_in[7];
    float* out = (float*)d_out;

    const int nNodes = in_sizes[0] / HIDDEN;   // 100000
    const int nEdges = in_sizes[1] / 2;        // 1250000

    // ws: meanb [N*64 bf16] | cb2 [N*64 bf16] | deg | rowPtr | cursor | csrSrc
    //     | blockSum     (~31.8 MB, same footprint as proven R3 layout)
    // cb1 (bf16 of x) lives in d_out-as-scratch (proven R9 pattern).
    unsigned short* meanb    = (unsigned short*)d_ws;
    unsigned short* cb2      = meanb + (size_t)nNodes * HIDDEN;
    int*            deg      = (int*)(cb2 + (size_t)nNodes * HIDDEN);
    int*            rowPtr   = deg + (nNodes + 1);
    int*            cursor   = rowPtr + (nNodes + 1);
    int*            csrSrc   = cursor + nNodes;
    int*            blockSum = csrSrc + nEdges;
    unsigned short* cb1      = (unsigned short*)d_out;

    const int nTiles  = (nNodes + TN - 1) / TN;       // 1563
    const int nChunks = (nNodes + 255) / 256;         // 391
    const int nFeat8  = nNodes * HIDDEN / 8;
    const int aggGrid = (nNodes + 3) / 4;

    // ---- CSR build (shared by both layers) ----
    hipMemsetAsync(deg, 0, (size_t)(nNodes + 1) * sizeof(int), stream);
    k_hist<<<2048, 256, 0, stream>>>(ei, deg, nEdges);
    k_scan1<<<nChunks, 256, 0, stream>>>(deg, rowPtr, blockSum, nNodes);
    k_scan2<<<1, 512, 0, stream>>>(blockSum, rowPtr, nChunks, nNodes);
    k_scan3<<<nChunks, 256, 0, stream>>>(rowPtr, cursor, blockSum, nNodes);
    k_fill<<<2048, 256, 0, stream>>>(ei, cursor, csrSrc, nEdges);

    // ---- layer 1: cb2 = bf16(relu(mean(x)@W1l + b1l + x@W1r)) ----
    k_tobf16<<<2048, 256, 0, stream>>>(x, cb1, nFeat8);
    k_agg<<<aggGrid, 256, 0, stream>>>(cb1, rowPtr, csrSrc, meanb, nNodes);
    k_out<true, true><<<nTiles, 256, 0, stream>>>(
        meanb, cb1, W1l, b1l, W1r, nullptr, cb2, nNodes);

    // ---- layer 2: out = mean(h)@W2l + b2l + h@W2r  (h = cb2) ----
    k_agg<<<aggGrid, 256, 0, stream>>>(cb2, rowPtr, csrSrc, meanb, nNodes);
    k_out<false, false><<<nTiles, 256, 0, stream>>>(
        meanb, cb2, W2l, b2l, W2r, out, nullptr, nNodes);
}